// Round 13
// baseline (108.006 us; speedup 1.0000x reference)
//
#include <hip/hip_runtime.h>

#define NB 8
#define LL 256
#define DD 256

typedef __attribute__((ext_vector_type(8))) short short8v;  // 8 bf16 (4 VGPR)
typedef __attribute__((ext_vector_type(4))) float f32x4;
typedef __attribute__((ext_vector_type(2))) float f32x2;

#if defined(__has_builtin)
#if __has_builtin(__builtin_elementwise_fma) && __has_builtin(__builtin_elementwise_max)
#define USE_PK 1
#endif
#endif

__device__ __forceinline__ uint f2bf2(float lo, float hi) {
  uint a = __float_as_uint(lo), b = __float_as_uint(hi);
  uint ra = (a + 0x7FFFu + ((a >> 16) & 1u)) >> 16;
  uint rb = (b + 0x7FFFu + ((b >> 16) & 1u)) & 0xFFFF0000u;
  return ra | rb;
}

// ---------------------------------------------------------------------------
// Kernel 1: A = Q Wa^T, Bm = Q Wb^T, Hj = Q Wd^T (fp32 into ws) via bf16 MFMA.
// Full-K staged once into padded LDS, ONE barrier, 16 back-to-back MFMA.
// IDENTICAL to R12. Launched 3x this round as a timing diagnostic (idempotent
// — writes the same values every launch; graph nodes on one stream serialize).
// ---------------------------------------------------------------------------
__global__ __launch_bounds__(256, 3) void gemm3_mfma(
    const float* __restrict__ Q, const float* __restrict__ Wa,
    const float* __restrict__ Wb, const float* __restrict__ Wd,
    const int* __restrict__ wl, const int* __restrict__ sdep,
    float* __restrict__ A, float* __restrict__ Bm, float* __restrict__ Hj,
    float* __restrict__ tail) {
  const int mt = blockIdx.x, nt = blockIdx.y, z = blockIdx.z;
  const int bid = mt + 32 * (nt + 8 * z);  // 0..767
  const float* __restrict__ W = (z == 0) ? Wa : (z == 1) ? Wb : Wd;
  float* __restrict__ Out = (z == 0) ? A : (z == 1) ? Bm : Hj;

  __shared__ __align__(16) ushort Qs[64][264];   // 33.8 KB, row 528B
  __shared__ __align__(16) ushort Wsh[32][264];  // 16.9 KB

  const int tid = threadIdx.x;
  const int m0 = mt * 64, n0 = nt * 32;

  // ---- stage Q (64 rows x 256 k): thread -> row tid>>2, 8 chunks of 8 ----
  {
    const int row = tid >> 2, kcb = (tid & 3) * 8;
    const float* src = &Q[(size_t)(m0 + row) * DD];
#pragma unroll
    for (int u = 0; u < 8; ++u) {
      int kc = kcb + u * 32;
      float4 q0 = *(const float4*)&src[kc];
      float4 q1 = *(const float4*)&src[kc + 4];
      uint4 pk = make_uint4(f2bf2(q0.x, q0.y), f2bf2(q0.z, q0.w),
                            f2bf2(q1.x, q1.y), f2bf2(q1.z, q1.w));
      *(uint4*)&Qs[row][kc] = pk;
    }
  }
  // ---- stage W (32 rows x 256 k): thread -> row tid>>3, 4 chunks of 8 ----
  {
    const int row = tid >> 3, kcb = (tid & 7) * 8;
    const float* src = &W[(size_t)(n0 + row) * DD];
#pragma unroll
    for (int u = 0; u < 4; ++u) {
      int kc = kcb + u * 64;
      float4 w0 = *(const float4*)&src[kc];
      float4 w1 = *(const float4*)&src[kc + 4];
      uint4 pw = make_uint4(f2bf2(w0.x, w0.y), f2bf2(w0.z, w0.w),
                            f2bf2(w1.x, w1.y), f2bf2(w1.z, w1.w));
      *(uint4*)&Wsh[row][kc] = pw;
    }
  }
  __syncthreads();  // the ONLY barrier

  const int w = tid >> 6, lane = tid & 63;
  const int wm = w >> 1, wn = w & 1;
  const int fr = lane & 15, hi = lane >> 4;

  f32x4 acc[2] = {};
#pragma unroll
  for (int k8 = 0; k8 < 8; ++k8) {
    short8v a0 = *(const short8v*)&Qs[wm * 32 + fr][k8 * 32 + hi * 8];
    short8v a1 = *(const short8v*)&Qs[wm * 32 + 16 + fr][k8 * 32 + hi * 8];
    short8v b0 = *(const short8v*)&Wsh[wn * 16 + fr][k8 * 32 + hi * 8];
    acc[0] = __builtin_amdgcn_mfma_f32_16x16x32_bf16(a0, b0, acc[0], 0, 0, 0);
    acc[1] = __builtin_amdgcn_mfma_f32_16x16x32_bf16(a1, b0, acc[1], 0, 0, 0);
  }

  const int rbase = m0 + wm * 32 + hi * 4;
  const int cbase = n0 + wn * 16 + fr;
#pragma unroll
  for (int i = 0; i < 2; ++i)
#pragma unroll
    for (int r = 0; r < 4; ++r)
      Out[(size_t)(rbase + i * 16 + r) * DD + cbase] = acc[i][r];

  // ---- tail: sdep (131072 int4) + 8 wordlens -> float ----
  {
    int t = bid * 256 + tid;
    if (t < 131072) {
      int4 s = *(const int4*)&sdep[(size_t)t * 4];
      float4 f;
      f.x = (float)s.x; f.y = (float)s.y; f.z = (float)s.z; f.w = (float)s.w;
      *(float4*)&tail[8 + (size_t)t * 4] = f;
    }
  }
  if (bid == 0 && tid < 8) tail[tid] = (float)wl[tid];
}

// ---------------------------------------------------------------------------
// Kernel 2: fused edge-score + masked softmax + aggregation + residual relu.
// BYTE-IDENTICAL to R11/R12 (measured 23.3us incl node overhead via R10).
// ---------------------------------------------------------------------------
__global__ __launch_bounds__(512, 4) void fused_kernel(
    const float* __restrict__ Q, const int* __restrict__ sdep,
    const float* __restrict__ w2, const float* __restrict__ A,
    const float* __restrict__ Bm, const float* __restrict__ Hj,
    float* __restrict__ out) {
  const int bid = blockIdx.x;
  const int b = bid & 7, it = bid >> 3;   // it in [0,64)
  const int i0 = it * 4;
  const int tid = threadIdx.x;
  const int w = tid >> 6, l = tid & 63;   // 8 waves
  const int j0 = w * 32;                  // wave's 32-j strip

  __shared__ float Ts[4][260];            // edge scores -> softmax weights
  __shared__ float Red[8][4][256];        // cross-wave agg partials (32 KB)

  // ---- Phase 1: edge scores ----
  {
    const int jp = l >> 4;   // 4 parallel j per wave
    const int cg = l & 15;   // c-chunk of 16
    f32x2 a2[4][8], wv2[8];
    const float* Ab = A + ((size_t)(b * LL + i0)) * DD + cg * 16;
#pragma unroll
    for (int r = 0; r < 4; ++r)
#pragma unroll
      for (int ch = 0; ch < 4; ++ch) {
        float4 t = *(const float4*)&Ab[(size_t)r * DD + ch * 4];
        a2[r][ch * 2] = (f32x2){t.x, t.y};
        a2[r][ch * 2 + 1] = (f32x2){t.z, t.w};
      }
#pragma unroll
    for (int ch = 0; ch < 4; ++ch) {
      float4 t = *(const float4*)&w2[cg * 16 + ch * 4];
      wv2[ch * 2] = (f32x2){t.x, t.y};
      wv2[ch * 2 + 1] = (f32x2){t.z, t.w};
    }

    const float* Bb = Bm + ((size_t)(b * LL + j0 + jp)) * DD + cg * 16;
#pragma unroll 2
    for (int s = 0; s < 8; ++s) {
      f32x2 bv2[8];
#pragma unroll
      for (int ch = 0; ch < 4; ++ch) {
        float4 t = *(const float4*)&Bb[(size_t)(s * 4) * DD + ch * 4];
        bv2[ch * 2] = (f32x2){t.x, t.y};
        bv2[ch * 2 + 1] = (f32x2){t.z, t.w};
      }
      f32x2 p2[4] = {};
#pragma unroll
      for (int u = 0; u < 8; ++u) {
        f32x2 bb = bv2[u], ww = wv2[u];
#pragma unroll
        for (int r = 0; r < 4; ++r) {
#ifdef USE_PK
          f32x2 sm = __builtin_elementwise_max(a2[r][u] + bb, (f32x2){0.f, 0.f});
          p2[r] = __builtin_elementwise_fma(ww, sm, p2[r]);
#else
          f32x2 t0 = a2[r][u] + bb;
          f32x2 sm = {fmaxf(t0.x, 0.f), fmaxf(t0.y, 0.f)};
          p2[r].x = fmaf(ww.x, sm.x, p2[r].x);
          p2[r].y = fmaf(ww.y, sm.y, p2[r].y);
#endif
        }
      }
      float p0 = p2[0].x + p2[0].y, p1 = p2[1].x + p2[1].y;
      float q2 = p2[2].x + p2[2].y, p3 = p2[3].x + p2[3].y;
#pragma unroll
      for (int m = 1; m <= 8; m <<= 1) {
        p0 += __shfl_xor(p0, m); p1 += __shfl_xor(p1, m);
        q2 += __shfl_xor(q2, m); p3 += __shfl_xor(p3, m);
      }
      float pv = p0;
      pv = (cg == 1) ? p1 : pv;
      pv = (cg == 2) ? q2 : pv;
      pv = (cg == 3) ? p3 : pv;
      if (cg < 4) Ts[cg][j0 + s * 4 + jp] = pv;  // 16 distinct banks: free
    }
  }
  __syncthreads();

  // ---- Phase 2: masked softmax (waves 0-3 -> rows 0-3) ----
  if (w < 4) {
    const int* sr = sdep + ((size_t)(b * LL + i0 + w)) * LL;
    float v[4];
    float m = -3.0e38f;
#pragma unroll
    for (int k = 0; k < 4; ++k) {
      int j = l + 64 * k;
      bool e = sr[j] > 0;
      v[k] = e ? Ts[w][j] : -3.0e38f;
      m = fmaxf(m, v[k]);
    }
#pragma unroll
    for (int off = 32; off >= 1; off >>= 1) m = fmaxf(m, __shfl_xor(m, off));
    float s = 0.f;
#pragma unroll
    for (int k = 0; k < 4; ++k) {
      float e = (v[k] > -1.0e30f) ? __expf(v[k] - m) : 0.f;
      v[k] = e;
      s += e;
    }
#pragma unroll
    for (int off = 32; off >= 1; off >>= 1) s += __shfl_xor(s, off);
    float inv = (s > 0.f) ? 1.0f / s : 0.f;
    // wave w is sole reader/writer of row w in this phase
#pragma unroll
    for (int k = 0; k < 4; ++k) Ts[w][l + 64 * k] = v[k] * inv;
  }
  __syncthreads();

  // ---- Phase 3: aggregation (wave w sums its 32-j strip, all 4 rows) ----
  {
    const float* Hb = Hj + ((size_t)(b * LL + j0)) * DD + l * 4;
    float acc[4][4] = {};
#pragma unroll 2
    for (int j4 = 0; j4 < 8; ++j4) {
      float tw0[4], tw1[4], tw2[4], tw3[4];
      *(float4*)tw0 = *(const float4*)&Ts[0][j0 + j4 * 4];
      *(float4*)tw1 = *(const float4*)&Ts[1][j0 + j4 * 4];
      *(float4*)tw2 = *(const float4*)&Ts[2][j0 + j4 * 4];
      *(float4*)tw3 = *(const float4*)&Ts[3][j0 + j4 * 4];
#pragma unroll
      for (int u = 0; u < 4; ++u) {
        float4 h = *(const float4*)&Hb[(size_t)(j4 * 4 + u) * DD];
        acc[0][0] = fmaf(tw0[u], h.x, acc[0][0]);
        acc[0][1] = fmaf(tw0[u], h.y, acc[0][1]);
        acc[0][2] = fmaf(tw0[u], h.z, acc[0][2]);
        acc[0][3] = fmaf(tw0[u], h.w, acc[0][3]);
        acc[1][0] = fmaf(tw1[u], h.x, acc[1][0]);
        acc[1][1] = fmaf(tw1[u], h.y, acc[1][1]);
        acc[1][2] = fmaf(tw1[u], h.z, acc[1][2]);
        acc[1][3] = fmaf(tw1[u], h.w, acc[1][3]);
        acc[2][0] = fmaf(tw2[u], h.x, acc[2][0]);
        acc[2][1] = fmaf(tw2[u], h.y, acc[2][1]);
        acc[2][2] = fmaf(tw2[u], h.z, acc[2][2]);
        acc[2][3] = fmaf(tw2[u], h.w, acc[2][3]);
        acc[3][0] = fmaf(tw3[u], h.x, acc[3][0]);
        acc[3][1] = fmaf(tw3[u], h.y, acc[3][1]);
        acc[3][2] = fmaf(tw3[u], h.z, acc[3][2]);
        acc[3][3] = fmaf(tw3[u], h.w, acc[3][3]);
      }
    }
#pragma unroll
    for (int r = 0; r < 4; ++r)
      *(float4*)&Red[w][r][l * 4] = *(float4*)acc[r];
  }
  __syncthreads();

  // ---- Phase 4: cross-wave reduce (8 strips) + residual relu ----
  if (tid < 256) {
    const int r = tid >> 6, q = tid & 63;
    float4 s0 = *(const float4*)&Red[0][r][q * 4];
    float4 s1 = *(const float4*)&Red[1][r][q * 4];
    float4 s2 = *(const float4*)&Red[2][r][q * 4];
    float4 s3 = *(const float4*)&Red[3][r][q * 4];
    float4 s4 = *(const float4*)&Red[4][r][q * 4];
    float4 s5 = *(const float4*)&Red[5][r][q * 4];
    float4 s6 = *(const float4*)&Red[6][r][q * 4];
    float4 s7 = *(const float4*)&Red[7][r][q * 4];
    size_t off = ((size_t)(b * LL + i0 + r)) * DD + q * 4;
    float4 qv = *(const float4*)&Q[off];
    float4 o;
    o.x = fmaxf(qv.x + ((s0.x + s1.x) + (s2.x + s3.x)) +
                        ((s4.x + s5.x) + (s6.x + s7.x)), 0.f);
    o.y = fmaxf(qv.y + ((s0.y + s1.y) + (s2.y + s3.y)) +
                        ((s4.y + s5.y) + (s6.y + s7.y)), 0.f);
    o.z = fmaxf(qv.z + ((s0.z + s1.z) + (s2.z + s3.z)) +
                        ((s4.z + s5.z) + (s6.z + s7.z)), 0.f);
    o.w = fmaxf(qv.w + ((s0.w + s1.w) + (s2.w + s3.w)) +
                        ((s4.w + s5.w) + (s6.w + s7.w)), 0.f);
    *(float4*)&out[off] = o;
  }
}

extern "C" void kernel_launch(void* const* d_in, const int* in_sizes, int n_in,
                              void* d_out, int out_size, void* d_ws, size_t ws_size,
                              hipStream_t stream) {
  const float* Q    = (const float*)d_in[0];
  const int*   wl   = (const int*)d_in[1];
  const int*   sdep = (const int*)d_in[2];
  const float* Wa   = (const float*)d_in[3];
  const float* Wb   = (const float*)d_in[4];
  const float* w2   = (const float*)d_in[5];
  const float* Wd   = (const float*)d_in[6];
  float* out = (float*)d_out;
  float* ws  = (float*)d_ws;

  float* A  = ws;              // [2048][256] fp32
  float* Bm = ws + 524288;     // [2048][256] fp32
  float* Hj = ws + 1048576;    // [2048][256] fp32
  float* tail = out + (size_t)NB * LL * DD;

  // DIAGNOSTIC (this round): gemm launched 3x (idempotent). The dur_us delta
  // vs the 1x baseline (97.1 us) = 2 * t_gemm + 2 * node overhead.
  gemm3_mfma<<<dim3(32, 8, 3), 256, 0, stream>>>(Q, Wa, Wb, Wd, wl, sdep,
                                                 A, Bm, Hj, tail);
  gemm3_mfma<<<dim3(32, 8, 3), 256, 0, stream>>>(Q, Wa, Wb, Wd, wl, sdep,
                                                 A, Bm, Hj, tail);
  gemm3_mfma<<<dim3(32, 8, 3), 256, 0, stream>>>(Q, Wa, Wb, Wd, wl, sdep,
                                                 A, Bm, Hj, tail);
  fused_kernel<<<512, 512, 0, stream>>>(Q, sdep, w2, A, Bm, Hj, out);
}

// Round 14
// 96.075 us; speedup vs baseline: 1.1242x; 1.1242x over previous
//
#include <hip/hip_runtime.h>

#define NB 8
#define LL 256
#define DD 256

typedef __attribute__((ext_vector_type(8))) short short8v;  // 8 bf16 (4 VGPR)
typedef __attribute__((ext_vector_type(4))) float f32x4;
typedef __attribute__((ext_vector_type(2))) float f32x2;

#if defined(__has_builtin)
#if __has_builtin(__builtin_elementwise_fma) && __has_builtin(__builtin_elementwise_max)
#define USE_PK 1
#endif
#endif

__device__ __forceinline__ uint f2bf2(float lo, float hi) {
  uint a = __float_as_uint(lo), b = __float_as_uint(hi);
  uint ra = (a + 0x7FFFu + ((a >> 16) & 1u)) >> 16;
  uint rb = (b + 0x7FFFu + ((b >> 16) & 1u)) & 0xFFFF0000u;
  return ra | rb;
}
__device__ __forceinline__ ushort f2bf(float f) {
  uint u = __float_as_uint(f);
  return (ushort)((u + 0x7FFFu + ((u >> 16) & 1u)) >> 16);
}
// one packed uint (2 bf16) -> f32x2 {lo, hi}
__device__ __forceinline__ f32x2 bf2f2(uint u) {
  return (f32x2){__uint_as_float(u << 16), __uint_as_float(u & 0xFFFF0000u)};
}

// ---------------------------------------------------------------------------
// Kernel 1: A = Q Wa^T (fp32), Bm = Q Wb^T (bf16), Hj = Q Wd^T (bf16).
// bf16 intermediates HALVE the fused kernel's L2 panel traffic (the measured
// bottleneck: 256MB -> 128MB). Full-K padded-LDS single-barrier MFMA design
// unchanged from R12 (measured gemm+node = 5.5us). Tail work unchanged.
// ---------------------------------------------------------------------------
__global__ __launch_bounds__(256, 3) void gemm3_mfma(
    const float* __restrict__ Q, const float* __restrict__ Wa,
    const float* __restrict__ Wb, const float* __restrict__ Wd,
    const int* __restrict__ wl, const int* __restrict__ sdep,
    float* __restrict__ A, ushort* __restrict__ Bmh, ushort* __restrict__ Hjh,
    float* __restrict__ tail) {
  const int mt = blockIdx.x, nt = blockIdx.y, z = blockIdx.z;
  const int bid = mt + 32 * (nt + 8 * z);  // 0..767
  const float* __restrict__ W = (z == 0) ? Wa : (z == 1) ? Wb : Wd;

  __shared__ __align__(16) ushort Qs[64][264];   // 33.8 KB, row 528B
  __shared__ __align__(16) ushort Wsh[32][264];  // 16.9 KB

  const int tid = threadIdx.x;
  const int m0 = mt * 64, n0 = nt * 32;

  // ---- stage Q (64 rows x 256 k) ----
  {
    const int row = tid >> 2, kcb = (tid & 3) * 8;
    const float* src = &Q[(size_t)(m0 + row) * DD];
#pragma unroll
    for (int u = 0; u < 8; ++u) {
      int kc = kcb + u * 32;
      float4 q0 = *(const float4*)&src[kc];
      float4 q1 = *(const float4*)&src[kc + 4];
      uint4 pk = make_uint4(f2bf2(q0.x, q0.y), f2bf2(q0.z, q0.w),
                            f2bf2(q1.x, q1.y), f2bf2(q1.z, q1.w));
      *(uint4*)&Qs[row][kc] = pk;
    }
  }
  // ---- stage W (32 rows x 256 k) ----
  {
    const int row = tid >> 3, kcb = (tid & 7) * 8;
    const float* src = &W[(size_t)(n0 + row) * DD];
#pragma unroll
    for (int u = 0; u < 4; ++u) {
      int kc = kcb + u * 64;
      float4 w0 = *(const float4*)&src[kc];
      float4 w1 = *(const float4*)&src[kc + 4];
      uint4 pw = make_uint4(f2bf2(w0.x, w0.y), f2bf2(w0.z, w0.w),
                            f2bf2(w1.x, w1.y), f2bf2(w1.z, w1.w));
      *(uint4*)&Wsh[row][kc] = pw;
    }
  }
  __syncthreads();  // the ONLY barrier

  const int w = tid >> 6, lane = tid & 63;
  const int wm = w >> 1, wn = w & 1;
  const int fr = lane & 15, hi = lane >> 4;

  f32x4 acc[2] = {};
#pragma unroll
  for (int k8 = 0; k8 < 8; ++k8) {
    short8v a0 = *(const short8v*)&Qs[wm * 32 + fr][k8 * 32 + hi * 8];
    short8v a1 = *(const short8v*)&Qs[wm * 32 + 16 + fr][k8 * 32 + hi * 8];
    short8v b0 = *(const short8v*)&Wsh[wn * 16 + fr][k8 * 32 + hi * 8];
    acc[0] = __builtin_amdgcn_mfma_f32_16x16x32_bf16(a0, b0, acc[0], 0, 0, 0);
    acc[1] = __builtin_amdgcn_mfma_f32_16x16x32_bf16(a1, b0, acc[1], 0, 0, 0);
  }

  const int rbase = m0 + wm * 32 + hi * 4;
  const int cbase = n0 + wn * 16 + fr;
  if (z == 0) {
#pragma unroll
    for (int i = 0; i < 2; ++i)
#pragma unroll
      for (int r = 0; r < 4; ++r)
        A[(size_t)(rbase + i * 16 + r) * DD + cbase] = acc[i][r];
  } else {
    ushort* __restrict__ Outh = (z == 1) ? Bmh : Hjh;
#pragma unroll
    for (int i = 0; i < 2; ++i)
#pragma unroll
      for (int r = 0; r < 4; ++r)
        Outh[(size_t)(rbase + i * 16 + r) * DD + cbase] = f2bf(acc[i][r]);
  }

  // ---- tail: sdep (131072 int4) + 8 wordlens -> float ----
  {
    int t = bid * 256 + tid;
    if (t < 131072) {
      int4 s = *(const int4*)&sdep[(size_t)t * 4];
      float4 f;
      f.x = (float)s.x; f.y = (float)s.y; f.z = (float)s.z; f.w = (float)s.w;
      *(float4*)&tail[8 + (size_t)t * 4] = f;
    }
  }
  if (bid == 0 && tid < 8) tail[tid] = (float)wl[tid];
}

// ---------------------------------------------------------------------------
// Kernel 2: fused edge-score + masked softmax + aggregation + residual relu.
// Same structure as R11 (512 blocks x 512 thr, 4-row i-tiles, 32-j strips),
// but Bm/Hj panels are now bf16: L2 bytes and load instrs halved; unpack via
// 2 bit-ops/pair feeding the packed-f32 pipeline.
// ---------------------------------------------------------------------------
__global__ __launch_bounds__(512, 4) void fused_kernel(
    const float* __restrict__ Q, const int* __restrict__ sdep,
    const float* __restrict__ w2, const float* __restrict__ A,
    const ushort* __restrict__ Bmh, const ushort* __restrict__ Hjh,
    float* __restrict__ out) {
  const int bid = blockIdx.x;
  const int b = bid & 7, it = bid >> 3;   // it in [0,64)
  const int i0 = it * 4;
  const int tid = threadIdx.x;
  const int w = tid >> 6, l = tid & 63;   // 8 waves
  const int j0 = w * 32;                  // wave's 32-j strip

  __shared__ float Ts[4][260];            // edge scores -> softmax weights
  __shared__ float Red[8][4][256];        // cross-wave agg partials (32 KB)

  // ---- Phase 1: edge scores ----
  {
    const int jp = l >> 4;   // 4 parallel j per wave
    const int cg = l & 15;   // c-chunk of 16
    f32x2 a2[4][8], wv2[8];
    const float* Ab = A + ((size_t)(b * LL + i0)) * DD + cg * 16;
#pragma unroll
    for (int r = 0; r < 4; ++r)
#pragma unroll
      for (int ch = 0; ch < 4; ++ch) {
        float4 t = *(const float4*)&Ab[(size_t)r * DD + ch * 4];
        a2[r][ch * 2] = (f32x2){t.x, t.y};
        a2[r][ch * 2 + 1] = (f32x2){t.z, t.w};
      }
#pragma unroll
    for (int ch = 0; ch < 4; ++ch) {
      float4 t = *(const float4*)&w2[cg * 16 + ch * 4];
      wv2[ch * 2] = (f32x2){t.x, t.y};
      wv2[ch * 2 + 1] = (f32x2){t.z, t.w};
    }

    const ushort* Bb = Bmh + ((size_t)(b * LL + j0 + jp)) * DD + cg * 16;
#pragma unroll 2
    for (int s = 0; s < 8; ++s) {
      uint4 u0 = *(const uint4*)&Bb[(size_t)(s * 4) * DD];      // c 0..7
      uint4 u1 = *(const uint4*)&Bb[(size_t)(s * 4) * DD + 8];  // c 8..15
      f32x2 bv2[8];
      bv2[0] = bf2f2(u0.x); bv2[1] = bf2f2(u0.y);
      bv2[2] = bf2f2(u0.z); bv2[3] = bf2f2(u0.w);
      bv2[4] = bf2f2(u1.x); bv2[5] = bf2f2(u1.y);
      bv2[6] = bf2f2(u1.z); bv2[7] = bf2f2(u1.w);
      f32x2 p2[4] = {};
#pragma unroll
      for (int u = 0; u < 8; ++u) {
        f32x2 bb = bv2[u], ww = wv2[u];
#pragma unroll
        for (int r = 0; r < 4; ++r) {
#ifdef USE_PK
          f32x2 sm = __builtin_elementwise_max(a2[r][u] + bb, (f32x2){0.f, 0.f});
          p2[r] = __builtin_elementwise_fma(ww, sm, p2[r]);
#else
          f32x2 t0 = a2[r][u] + bb;
          f32x2 sm = {fmaxf(t0.x, 0.f), fmaxf(t0.y, 0.f)};
          p2[r].x = fmaf(ww.x, sm.x, p2[r].x);
          p2[r].y = fmaf(ww.y, sm.y, p2[r].y);
#endif
        }
      }
      float p0 = p2[0].x + p2[0].y, p1 = p2[1].x + p2[1].y;
      float q2 = p2[2].x + p2[2].y, p3 = p2[3].x + p2[3].y;
#pragma unroll
      for (int m = 1; m <= 8; m <<= 1) {
        p0 += __shfl_xor(p0, m); p1 += __shfl_xor(p1, m);
        q2 += __shfl_xor(q2, m); p3 += __shfl_xor(p3, m);
      }
      float pv = p0;
      pv = (cg == 1) ? p1 : pv;
      pv = (cg == 2) ? q2 : pv;
      pv = (cg == 3) ? p3 : pv;
      if (cg < 4) Ts[cg][j0 + s * 4 + jp] = pv;  // 16 distinct banks: free
    }
  }
  __syncthreads();

  // ---- Phase 2: masked softmax (waves 0-3 -> rows 0-3) ----
  if (w < 4) {
    const int* sr = sdep + ((size_t)(b * LL + i0 + w)) * LL;
    float v[4];
    float m = -3.0e38f;
#pragma unroll
    for (int k = 0; k < 4; ++k) {
      int j = l + 64 * k;
      bool e = sr[j] > 0;
      v[k] = e ? Ts[w][j] : -3.0e38f;
      m = fmaxf(m, v[k]);
    }
#pragma unroll
    for (int off = 32; off >= 1; off >>= 1) m = fmaxf(m, __shfl_xor(m, off));
    float s = 0.f;
#pragma unroll
    for (int k = 0; k < 4; ++k) {
      float e = (v[k] > -1.0e30f) ? __expf(v[k] - m) : 0.f;
      v[k] = e;
      s += e;
    }
#pragma unroll
    for (int off = 32; off >= 1; off >>= 1) s += __shfl_xor(s, off);
    float inv = (s > 0.f) ? 1.0f / s : 0.f;
    // wave w is sole reader/writer of row w in this phase
#pragma unroll
    for (int k = 0; k < 4; ++k) Ts[w][l + 64 * k] = v[k] * inv;
  }
  __syncthreads();

  // ---- Phase 3: aggregation (wave w sums its 32-j strip, all 4 rows) ----
  {
    const ushort* Hb = Hjh + ((size_t)(b * LL + j0)) * DD + l * 4;
    float acc[4][4] = {};
#pragma unroll 2
    for (int j4 = 0; j4 < 8; ++j4) {
      float tw0[4], tw1[4], tw2[4], tw3[4];
      *(float4*)tw0 = *(const float4*)&Ts[0][j0 + j4 * 4];
      *(float4*)tw1 = *(const float4*)&Ts[1][j0 + j4 * 4];
      *(float4*)tw2 = *(const float4*)&Ts[2][j0 + j4 * 4];
      *(float4*)tw3 = *(const float4*)&Ts[3][j0 + j4 * 4];
#pragma unroll
      for (int u = 0; u < 4; ++u) {
        uint2 hu = *(const uint2*)&Hb[(size_t)(j4 * 4 + u) * DD];
        f32x2 hlo = bf2f2(hu.x), hhi = bf2f2(hu.y);
        float h0 = hlo.x, h1 = hlo.y, h2 = hhi.x, h3 = hhi.y;
        acc[0][0] = fmaf(tw0[u], h0, acc[0][0]);
        acc[0][1] = fmaf(tw0[u], h1, acc[0][1]);
        acc[0][2] = fmaf(tw0[u], h2, acc[0][2]);
        acc[0][3] = fmaf(tw0[u], h3, acc[0][3]);
        acc[1][0] = fmaf(tw1[u], h0, acc[1][0]);
        acc[1][1] = fmaf(tw1[u], h1, acc[1][1]);
        acc[1][2] = fmaf(tw1[u], h2, acc[1][2]);
        acc[1][3] = fmaf(tw1[u], h3, acc[1][3]);
        acc[2][0] = fmaf(tw2[u], h0, acc[2][0]);
        acc[2][1] = fmaf(tw2[u], h1, acc[2][1]);
        acc[2][2] = fmaf(tw2[u], h2, acc[2][2]);
        acc[2][3] = fmaf(tw2[u], h3, acc[2][3]);
        acc[3][0] = fmaf(tw3[u], h0, acc[3][0]);
        acc[3][1] = fmaf(tw3[u], h1, acc[3][1]);
        acc[3][2] = fmaf(tw3[u], h2, acc[3][2]);
        acc[3][3] = fmaf(tw3[u], h3, acc[3][3]);
      }
    }
#pragma unroll
    for (int r = 0; r < 4; ++r)
      *(float4*)&Red[w][r][l * 4] = *(float4*)acc[r];
  }
  __syncthreads();

  // ---- Phase 4: cross-wave reduce (8 strips) + residual relu ----
  if (tid < 256) {
    const int r = tid >> 6, q = tid & 63;
    float4 s0 = *(const float4*)&Red[0][r][q * 4];
    float4 s1 = *(const float4*)&Red[1][r][q * 4];
    float4 s2 = *(const float4*)&Red[2][r][q * 4];
    float4 s3 = *(const float4*)&Red[3][r][q * 4];
    float4 s4 = *(const float4*)&Red[4][r][q * 4];
    float4 s5 = *(const float4*)&Red[5][r][q * 4];
    float4 s6 = *(const float4*)&Red[6][r][q * 4];
    float4 s7 = *(const float4*)&Red[7][r][q * 4];
    size_t off = ((size_t)(b * LL + i0 + r)) * DD + q * 4;
    float4 qv = *(const float4*)&Q[off];
    float4 o;
    o.x = fmaxf(qv.x + ((s0.x + s1.x) + (s2.x + s3.x)) +
                        ((s4.x + s5.x) + (s6.x + s7.x)), 0.f);
    o.y = fmaxf(qv.y + ((s0.y + s1.y) + (s2.y + s3.y)) +
                        ((s4.y + s5.y) + (s6.y + s7.y)), 0.f);
    o.z = fmaxf(qv.z + ((s0.z + s1.z) + (s2.z + s3.z)) +
                        ((s4.z + s5.z) + (s6.z + s7.z)), 0.f);
    o.w = fmaxf(qv.w + ((s0.w + s1.w) + (s2.w + s3.w)) +
                        ((s4.w + s5.w) + (s6.w + s7.w)), 0.f);
    *(float4*)&out[off] = o;
  }
}

extern "C" void kernel_launch(void* const* d_in, const int* in_sizes, int n_in,
                              void* d_out, int out_size, void* d_ws, size_t ws_size,
                              hipStream_t stream) {
  const float* Q    = (const float*)d_in[0];
  const int*   wl   = (const int*)d_in[1];
  const int*   sdep = (const int*)d_in[2];
  const float* Wa   = (const float*)d_in[3];
  const float* Wb   = (const float*)d_in[4];
  const float* w2   = (const float*)d_in[5];
  const float* Wd   = (const float*)d_in[6];
  float* out = (float*)d_out;
  float* ws  = (float*)d_ws;

  float*  A   = ws;                           // [2048][256] fp32 (2 MB)
  ushort* Bmh = (ushort*)(ws + 524288);       // [2048][256] bf16 (1 MB)
  ushort* Hjh = Bmh + (size_t)NB * LL * DD;   // [2048][256] bf16 (1 MB)
  float* tail = out + (size_t)NB * LL * DD;

  gemm3_mfma<<<dim3(32, 8, 3), 256, 0, stream>>>(Q, Wa, Wb, Wd, wl, sdep,
                                                 A, Bmh, Hjh, tail);
  fused_kernel<<<512, 512, 0, stream>>>(Q, sdep, w2, A, Bmh, Hjh, out);
}